// Round 7
// baseline (137.483 us; speedup 1.0000x reference)
//
#include <hip/hip_runtime.h>

#define NUSR 8192
#define HDIM 256

typedef __attribute__((ext_vector_type(8))) __bf16 bf16x8;
typedef __attribute__((ext_vector_type(4))) float f32x4;

union frag_u { bf16x8 v; unsigned short u[8]; unsigned int d[4]; };

// f32 -> bf16 RNE
__device__ __forceinline__ unsigned int f2bf(float f) {
  unsigned u = __builtin_bit_cast(unsigned, f);
  u += 0x7FFFu + ((u >> 16) & 1u);
  return u >> 16;
}
__device__ __forceinline__ unsigned int f2bf2(float lo, float hi) {
  return f2bf(lo) | (f2bf(hi) << 16);
}
__device__ __forceinline__ float sigmoidf_fast(float x) {
  float e = __builtin_amdgcn_exp2f(x * -1.44269504088896340736f);
  return __builtin_amdgcn_rcpf(1.0f + e);
}

// PX layout (proj in MFMA-B fragment order), ushort offsets:
//   PX[(col>>4)*4096 + (k>>5)*512 + ((k>>3)&3)*128 + (col&15)*8 + (k&7)]
// -> B-frag for (col16 ct, kb) = 16B at PX + ct*4096 + kb*512 + lane*8 (lane-linear).
// WX layout (W in MFMA-A fragment order):
//   WX[(st*8+kb)*512 + lane*8 + j] = W[st*16 + (lane&15)][kb*32 + (lane>>4)*8 + j]

// ---------------------------------------------------------------------------
// k0: prep — yabf = bf16(ya); WX = fragment-ordered bf16(W); svec = 0.
// ---------------------------------------------------------------------------
__global__ __launch_bounds__(256) void k0_prep(
    const float* __restrict__ ya, const float* __restrict__ W,
    unsigned short* __restrict__ yabf, unsigned short* __restrict__ WX,
    float* __restrict__ svec)
{
  const int gid = blockIdx.x * 256 + threadIdx.x; // 0..16383

  {
    const float4* src = (const float4*)ya;
    uint4* dst = (uint4*)yabf;
#pragma unroll
    for (int u = 0; u < 16; ++u) {
      int d = u * 16384 + gid;
      float4 a = src[d * 2];
      float4 b = src[d * 2 + 1];
      uint4 o = { f2bf2(a.x, a.y), f2bf2(a.z, a.w),
                  f2bf2(b.x, b.y), f2bf2(b.z, b.w) };
      dst[d] = o;
    }
  }

  if (gid < 8192) {
    int st = gid >> 9;
    int kb = (gid >> 6) & 7;
    int l  = gid & 63;
    int i  = l & 15, q = l >> 4;
    const float* wr = W + (size_t)(st * 16 + i) * HDIM + kb * 32 + q * 8;
    float4 w0 = *(const float4*)wr;
    float4 w1 = *(const float4*)(wr + 4);
    uint4 o = { f2bf2(w0.x, w0.y), f2bf2(w0.z, w0.w),
                f2bf2(w1.x, w1.y), f2bf2(w1.z, w1.w) };
    *(uint4*)(WX + (size_t)gid * 8) = o;
  }

  if (gid < 8192) svec[gid] = 0.f;
}

// ---------------------------------------------------------------------------
// k1: PX = fragment-ordered bf16( proj = yb.W^T + b )
// grid 512 x 256 thr. wave wid: jg = wid>>2 (16 yb rows), qtr = wid&3.
// A = WX frags (bf16 16B lane-linear), B = yb rows (fp32->bf16 in-register).
// ---------------------------------------------------------------------------
__global__ __launch_bounds__(256) void k1_proj(
    const float* __restrict__ yb, const unsigned short* __restrict__ WX,
    const float* __restrict__ bvec, unsigned short* __restrict__ PX)
{
  const int tid  = threadIdx.x;
  const int lane = tid & 63;
  const int w    = tid >> 6;
  const int q    = lane >> 4;
  const int i    = lane & 15;
  const int wid  = blockIdx.x * 4 + w;
  const int jg   = wid >> 2;
  const int qtr  = wid & 3;

  frag_u B[8];
  {
    const float* ybrow = yb + (size_t)(jg * 16 + i) * HDIM;
#pragma unroll
    for (int kb = 0; kb < 8; ++kb) {
      float4 v0 = *(const float4*)&ybrow[kb * 32 + q * 8];
      float4 v1 = *(const float4*)&ybrow[kb * 32 + q * 8 + 4];
      B[kb].d[0] = f2bf2(v0.x, v0.y); B[kb].d[1] = f2bf2(v0.z, v0.w);
      B[kb].d[2] = f2bf2(v1.x, v1.y); B[kb].d[3] = f2bf2(v1.z, v1.w);
    }
  }

#pragma unroll
  for (int t = 0; t < 4; ++t) {
    const int st = qtr * 4 + t;
    f32x4 acc = {0.f, 0.f, 0.f, 0.f};
#pragma unroll
    for (int kb = 0; kb < 8; ++kb) {
      frag_u Af;
      Af.v = *(const bf16x8*)&WX[(size_t)(st * 8 + kb) * 512 + lane * 8];
      acc = __builtin_amdgcn_mfma_f32_16x16x32_bf16(Af.v, B[kb].v, acc, 0, 0, 0);
    }
    float4 bias = *(const float4*)&bvec[st * 16 + q * 4];
    unsigned v0 = f2bf2(acc[0] + bias.x, acc[1] + bias.y);
    unsigned v1 = f2bf2(acc[2] + bias.z, acc[3] + bias.w);
    size_t off = (size_t)jg * 4096 + (size_t)(st >> 1) * 512
               + (size_t)(((st & 1) << 1) | (q >> 1)) * 128 + i * 8 + ((q & 1) * 4);
    *(uint2*)(PX + off) = make_uint2(v0, v1);
  }
}

// ---------------------------------------------------------------------------
// k2: s[i] += sum_j sigmoid( ya[i] . proj[j] )
// grid (32,16) x 256 thr: 4 independent waves x 64 rows (A = 128 VGPR, held).
// NO LDS, NO barriers: B-frags are lane-linear 16B global loads from the
// L2-resident fragment-ordered PX, register double-buffered per 16-col tile.
// 32 MFMAs of slack per 8-load batch hides L2 latency (~200 cyc).
// ---------------------------------------------------------------------------
__global__ __launch_bounds__(256, 2) void k2_score(
    const unsigned short* __restrict__ yabf, const unsigned short* __restrict__ PX,
    float* __restrict__ svec)
{
  const int tid  = threadIdx.x;
  const int lane = tid & 63;
  const int w    = tid >> 6;
  const int quad = lane >> 4;
  const int l15  = lane & 15;
  const int rbase = blockIdx.x * 256 + w * 64;
  const int cg16  = blockIdx.y * 32;          // col16-group base (512 cols)

  // A-frags: 64 ya rows per wave, direct bf16 16B loads
  frag_u A[4][8];
#pragma unroll
  for (int g = 0; g < 4; ++g) {
    const unsigned short* src = yabf + (size_t)(rbase + g * 16 + l15) * HDIM;
#pragma unroll
    for (int kb = 0; kb < 8; ++kb)
      A[g][kb].v = *(const bf16x8*)&src[kb * 32 + quad * 8];
  }

  const unsigned short* pbase = PX + (size_t)cg16 * 4096 + lane * 8;

  float rs[4][4] = {{0.f,0.f,0.f,0.f},{0.f,0.f,0.f,0.f},
                    {0.f,0.f,0.f,0.f},{0.f,0.f,0.f,0.f}};

  frag_u B0[8], B1[8];
#pragma unroll
  for (int kb = 0; kb < 8; ++kb)
    B0[kb].v = *(const bf16x8*)&pbase[kb * 512];

  for (int it = 0; it < 32; ++it) {           // 32 col16-tiles (512 cols)
    frag_u* Bc = (it & 1) ? B1 : B0;
    frag_u* Bn = (it & 1) ? B0 : B1;
    if (it < 31) {
      const unsigned short* p = pbase + (size_t)(it + 1) * 4096;
#pragma unroll
      for (int kb = 0; kb < 8; ++kb)
        Bn[kb].v = *(const bf16x8*)&p[kb * 512];
    }
    f32x4 acc[4] = {{0.f,0.f,0.f,0.f},{0.f,0.f,0.f,0.f},
                    {0.f,0.f,0.f,0.f},{0.f,0.f,0.f,0.f}};
#pragma unroll
    for (int kb = 0; kb < 8; ++kb) {
#pragma unroll
      for (int g = 0; g < 4; ++g)
        acc[g] = __builtin_amdgcn_mfma_f32_16x16x32_bf16(A[g][kb].v, Bc[kb].v, acc[g], 0, 0, 0);
    }
#pragma unroll
    for (int g = 0; g < 4; ++g)
#pragma unroll
      for (int r = 0; r < 4; ++r)
        rs[g][r] += sigmoidf_fast(acc[g][r]);
  }

  // reduce over the 16 col-lanes within each quad group
#pragma unroll
  for (int off = 1; off < 16; off <<= 1)
#pragma unroll
    for (int g = 0; g < 4; ++g)
#pragma unroll
      for (int r = 0; r < 4; ++r)
        rs[g][r] += __shfl_xor(rs[g][r], off, 64);

  if (l15 == 0) {
#pragma unroll
    for (int g = 0; g < 4; ++g)
#pragma unroll
      for (int r = 0; r < 4; ++r)
        atomicAdd(&svec[rbase + g * 16 + quad * 4 + r], rs[g][r]);
  }
}

// ---------------------------------------------------------------------------
// k3: out[i][k] = s[i] / 256
// ---------------------------------------------------------------------------
__global__ __launch_bounds__(256) void k3_bcast(
    const float* __restrict__ svec, float* __restrict__ out)
{
  int idx = blockIdx.x * 256 + threadIdx.x;
  int row = idx >> 6;
  float v = svec[row] * (1.0f / 256.0f);
  float4 o = {v, v, v, v};
  ((float4*)out)[idx] = o;
}

extern "C" void kernel_launch(void* const* d_in, const int* in_sizes, int n_in,
                              void* d_out, int out_size, void* d_ws, size_t ws_size,
                              hipStream_t stream) {
  (void)in_sizes; (void)n_in; (void)out_size;
  const float* ya = (const float*)d_in[0];
  const float* yb = (const float*)d_in[1];
  const float* W  = (const float*)d_in[2];
  const float* bv = (const float*)d_in[3];
  float* out = (float*)d_out;

  char* ws = (char*)d_ws;
  unsigned short *PX, *yabf, *WX;
  float* svec;
  const size_t need = (8ull << 20) + (256ull << 10);
  if (ws_size >= need) {
    PX   = (unsigned short*)ws;
    yabf = (unsigned short*)(ws + (4 << 20));
    WX   = (unsigned short*)(ws + (8 << 20));
    svec = (float*)(ws + (8 << 20) + (128 << 10));
  } else {
    PX   = (unsigned short*)d_out;
    yabf = (unsigned short*)((char*)d_out + (4 << 20));
    WX   = (unsigned short*)ws;                 // 128 KB
    svec = (float*)(ws + (128 << 10));          // 32 KB
  }

  k0_prep<<<64, 256, 0, stream>>>(ya, W, yabf, WX, svec);
  k1_proj<<<512, 256, 0, stream>>>(yb, WX, bv, PX);
  k2_score<<<dim3(32, 16), 256, 0, stream>>>(yabf, PX, svec);
  k3_bcast<<<2048, 256, 0, stream>>>(svec, out);
}

// Round 8
// 116.591 us; speedup vs baseline: 1.1792x; 1.1792x over previous
//
#include <hip/hip_runtime.h>

#define NUSR 8192
#define HDIM 256

typedef __attribute__((ext_vector_type(8))) __bf16 bf16x8;
typedef __attribute__((ext_vector_type(4))) float f32x4;

union frag_u { bf16x8 v; unsigned short u[8]; unsigned int d[4]; };

// f32 -> bf16 RNE
__device__ __forceinline__ unsigned int f2bf(float f) {
  unsigned u = __builtin_bit_cast(unsigned, f);
  u += 0x7FFFu + ((u >> 16) & 1u);
  return u >> 16;
}
__device__ __forceinline__ unsigned int f2bf2(float lo, float hi) {
  return f2bf(lo) | (f2bf(hi) << 16);
}
__device__ __forceinline__ float sigmoidf_fast(float x) {
  float e = __builtin_amdgcn_exp2f(x * -1.44269504088896340736f);
  return __builtin_amdgcn_rcpf(1.0f + e);
}

// PX layout (proj in MFMA-B fragment order), ushort offsets:
//   PX[(col>>4)*4096 + (k>>5)*512 + ((k>>3)&3)*128 + (col&15)*8 + (k&7)]
// -> B-frag for (col16 ct, kb) = 16B at PX + ct*4096 + kb*512 + lane*8 (lane-linear).
// WX layout (W in MFMA-A fragment order):
//   WX[(st*8+kb)*512 + lane*8 + j] = W[st*16 + (lane&15)][kb*32 + (lane>>4)*8 + j]

// ---------------------------------------------------------------------------
// k0: prep — yabf = bf16(ya); WX = fragment-ordered bf16(W); svec = 0.
// ---------------------------------------------------------------------------
__global__ __launch_bounds__(256) void k0_prep(
    const float* __restrict__ ya, const float* __restrict__ W,
    unsigned short* __restrict__ yabf, unsigned short* __restrict__ WX,
    float* __restrict__ svec)
{
  const int gid = blockIdx.x * 256 + threadIdx.x; // 0..16383

  {
    const float4* src = (const float4*)ya;
    uint4* dst = (uint4*)yabf;
#pragma unroll
    for (int u = 0; u < 16; ++u) {
      int d = u * 16384 + gid;
      float4 a = src[d * 2];
      float4 b = src[d * 2 + 1];
      uint4 o = { f2bf2(a.x, a.y), f2bf2(a.z, a.w),
                  f2bf2(b.x, b.y), f2bf2(b.z, b.w) };
      dst[d] = o;
    }
  }

  if (gid < 8192) {
    int st = gid >> 9;
    int kb = (gid >> 6) & 7;
    int l  = gid & 63;
    int i  = l & 15, q = l >> 4;
    const float* wr = W + (size_t)(st * 16 + i) * HDIM + kb * 32 + q * 8;
    float4 w0 = *(const float4*)wr;
    float4 w1 = *(const float4*)(wr + 4);
    uint4 o = { f2bf2(w0.x, w0.y), f2bf2(w0.z, w0.w),
                f2bf2(w1.x, w1.y), f2bf2(w1.z, w1.w) };
    *(uint4*)(WX + (size_t)gid * 8) = o;
  }

  if (gid < 8192) svec[gid] = 0.f;
}

// ---------------------------------------------------------------------------
// k1: PX = fragment-ordered bf16( proj = yb.W^T + b )
// grid 512 x 256 thr. wave wid: jg = wid>>2 (16 yb rows), qtr = wid&3.
// ---------------------------------------------------------------------------
__global__ __launch_bounds__(256) void k1_proj(
    const float* __restrict__ yb, const unsigned short* __restrict__ WX,
    const float* __restrict__ bvec, unsigned short* __restrict__ PX)
{
  const int tid  = threadIdx.x;
  const int lane = tid & 63;
  const int w    = tid >> 6;
  const int q    = lane >> 4;
  const int i    = lane & 15;
  const int wid  = blockIdx.x * 4 + w;
  const int jg   = wid >> 2;
  const int qtr  = wid & 3;

  frag_u B[8];
  {
    const float* ybrow = yb + (size_t)(jg * 16 + i) * HDIM;
#pragma unroll
    for (int kb = 0; kb < 8; ++kb) {
      float4 v0 = *(const float4*)&ybrow[kb * 32 + q * 8];
      float4 v1 = *(const float4*)&ybrow[kb * 32 + q * 8 + 4];
      B[kb].d[0] = f2bf2(v0.x, v0.y); B[kb].d[1] = f2bf2(v0.z, v0.w);
      B[kb].d[2] = f2bf2(v1.x, v1.y); B[kb].d[3] = f2bf2(v1.z, v1.w);
    }
  }

#pragma unroll
  for (int t = 0; t < 4; ++t) {
    const int st = qtr * 4 + t;
    f32x4 acc = {0.f, 0.f, 0.f, 0.f};
#pragma unroll
    for (int kb = 0; kb < 8; ++kb) {
      frag_u Af;
      Af.v = *(const bf16x8*)&WX[(size_t)(st * 8 + kb) * 512 + lane * 8];
      acc = __builtin_amdgcn_mfma_f32_16x16x32_bf16(Af.v, B[kb].v, acc, 0, 0, 0);
    }
    float4 bias = *(const float4*)&bvec[st * 16 + q * 4];
    unsigned v0 = f2bf2(acc[0] + bias.x, acc[1] + bias.y);
    unsigned v1 = f2bf2(acc[2] + bias.z, acc[3] + bias.w);
    size_t off = (size_t)jg * 4096 + (size_t)(st >> 1) * 512
               + (size_t)(((st & 1) << 1) | (q >> 1)) * 128 + i * 8 + ((q & 1) * 4);
    *(uint2*)(PX + off) = make_uint2(v0, v1);
  }
}

// ---------------------------------------------------------------------------
// k2: s[i] += sum_j sigmoid( ya[i] . proj[j] )
// grid (32,16) x 256 thr: 4 waves x 64 rows (A = 128 regs, held whole kernel).
// Double-buffered LDS (2 x 16 KB, 32-col tiles): stage-loads for tile t+1 are
// issued AFTER the barrier that opens compute of tile t, so they overlap the
// full MFMA phase and the barrier's vmcnt(0) drain is nearly free.
// B-frag ds_read_b128 lane-linear (conflict-free); each feeds 4 MFMAs.
// ---------------------------------------------------------------------------
__global__ __launch_bounds__(256, 2) void k2_score(
    const unsigned short* __restrict__ yabf, const unsigned short* __restrict__ PX,
    float* __restrict__ svec)
{
  __shared__ __align__(16) unsigned short bs[2][8192]; // 2 x 16 KB
  const int tid  = threadIdx.x;
  const int lane = tid & 63;
  const int w    = tid >> 6;
  const int quad = lane >> 4;
  const int l15  = lane & 15;
  const int rbase = blockIdx.x * 256 + w * 64;
  const int cg16  = blockIdx.y * 32;          // col16-group base (512 cols)

  // A-frags: 64 ya rows per wave, direct bf16 16B loads
  frag_u A[4][8];
#pragma unroll
  for (int g = 0; g < 4; ++g) {
    const unsigned short* src = yabf + (size_t)(rbase + g * 16 + l15) * HDIM;
#pragma unroll
    for (int kb = 0; kb < 8; ++kb)
      A[g][kb].v = *(const bf16x8*)&src[kb * 32 + quad * 8];
  }

  const unsigned short* psrc = PX + (size_t)cg16 * 4096; // this block's 256 KB slice

  float rs[4][4] = {{0.f,0.f,0.f,0.f},{0.f,0.f,0.f,0.f},
                    {0.f,0.f,0.f,0.f},{0.f,0.f,0.f,0.f}};

  // stage tile 0 into buffer 0 (16 KB = 1024 x 16B chunks, 4 per thread)
#pragma unroll
  for (int p = 0; p < 4; ++p) {
    int c = p * 256 + tid;
    __builtin_amdgcn_global_load_lds(
        (const __attribute__((address_space(1))) unsigned int*)(const void*)(psrc + c * 8),
        (__attribute__((address_space(3))) unsigned int*)(void*)(&bs[0][0] + c * 8),
        16, 0, 0);
  }
  __syncthreads(); // tile 0 visible

  for (int t = 0; t < 16; ++t) {           // 16 tiles x 32 cols = 512 cols
    // issue stage of tile t+1 into the other buffer — overlaps compute below
    if (t < 15) {
      const unsigned short* src = psrc + (size_t)(t + 1) * 8192;
      unsigned short* dst = &bs[(t + 1) & 1][0];
#pragma unroll
      for (int p = 0; p < 4; ++p) {
        int c = p * 256 + tid;
        __builtin_amdgcn_global_load_lds(
            (const __attribute__((address_space(1))) unsigned int*)(const void*)(src + c * 8),
            (__attribute__((address_space(3))) unsigned int*)(void*)(dst + c * 8),
            16, 0, 0);
      }
    }
    // compute tile t from bs[t&1]
    const unsigned short* buf = &bs[t & 1][0];
#pragma unroll
    for (int tt = 0; tt < 2; ++tt) {
      f32x4 acc[4] = {{0.f,0.f,0.f,0.f},{0.f,0.f,0.f,0.f},
                      {0.f,0.f,0.f,0.f},{0.f,0.f,0.f,0.f}};
#pragma unroll
      for (int kb = 0; kb < 8; ++kb) {
        bf16x8 bfrag = *(const bf16x8*)&buf[(tt * 512 + kb * 64 + lane) * 8];
#pragma unroll
        for (int g = 0; g < 4; ++g)
          acc[g] = __builtin_amdgcn_mfma_f32_16x16x32_bf16(A[g][kb].v, bfrag, acc[g], 0, 0, 0);
      }
#pragma unroll
      for (int g = 0; g < 4; ++g)
#pragma unroll
        for (int r = 0; r < 4; ++r)
          rs[g][r] += sigmoidf_fast(acc[g][r]);
    }
    __syncthreads(); // drains t+1 loads (had full compute phase) + buffer reuse
  }

  // reduce over the 16 col-lanes within each quad group
#pragma unroll
  for (int off = 1; off < 16; off <<= 1)
#pragma unroll
    for (int g = 0; g < 4; ++g)
#pragma unroll
      for (int r = 0; r < 4; ++r)
        rs[g][r] += __shfl_xor(rs[g][r], off, 64);

  if (l15 == 0) {
#pragma unroll
    for (int g = 0; g < 4; ++g)
#pragma unroll
      for (int r = 0; r < 4; ++r)
        atomicAdd(&svec[rbase + g * 16 + quad * 4 + r], rs[g][r]);
  }
}

// ---------------------------------------------------------------------------
// k3: out[i][k] = s[i] / 256
// ---------------------------------------------------------------------------
__global__ __launch_bounds__(256) void k3_bcast(
    const float* __restrict__ svec, float* __restrict__ out)
{
  int idx = blockIdx.x * 256 + threadIdx.x;
  int row = idx >> 6;
  float v = svec[row] * (1.0f / 256.0f);
  float4 o = {v, v, v, v};
  ((float4*)out)[idx] = o;
}

extern "C" void kernel_launch(void* const* d_in, const int* in_sizes, int n_in,
                              void* d_out, int out_size, void* d_ws, size_t ws_size,
                              hipStream_t stream) {
  (void)in_sizes; (void)n_in; (void)out_size;
  const float* ya = (const float*)d_in[0];
  const float* yb = (const float*)d_in[1];
  const float* W  = (const float*)d_in[2];
  const float* bv = (const float*)d_in[3];
  float* out = (float*)d_out;

  char* ws = (char*)d_ws;
  unsigned short *PX, *yabf, *WX;
  float* svec;
  const size_t need = (8ull << 20) + (256ull << 10);
  if (ws_size >= need) {
    PX   = (unsigned short*)ws;
    yabf = (unsigned short*)(ws + (4 << 20));
    WX   = (unsigned short*)(ws + (8 << 20));
    svec = (float*)(ws + (8 << 20) + (128 << 10));
  } else {
    PX   = (unsigned short*)d_out;
    yabf = (unsigned short*)((char*)d_out + (4 << 20));
    WX   = (unsigned short*)ws;                 // 128 KB
    svec = (float*)(ws + (128 << 10));          // 32 KB
  }

  k0_prep<<<64, 256, 0, stream>>>(ya, W, yabf, WX, svec);
  k1_proj<<<512, 256, 0, stream>>>(yb, WX, bv, PX);
  k2_score<<<dim3(32, 16), 256, 0, stream>>>(yabf, PX, svec);
  k3_bcast<<<2048, 256, 0, stream>>>(svec, out);
}